// Round 9
// baseline (424.657 us; speedup 1.0000x reference)
//
#include <hip/hip_runtime.h>
#include <cmath>

#define BATCH 4
#define CH    512
#define HCH   256
#define NPIX  4096
#define L2E   1.44269504088896340736f

typedef __attribute__((ext_vector_type(8))) short bf16x8;
typedef __attribute__((ext_vector_type(4))) float f32x4;

#define MFMA16(a, b, c) __builtin_amdgcn_mfma_f32_16x16x32_bf16((a), (b), (c), 0, 0, 0)

__device__ __forceinline__ unsigned short f2bf(float f) {
    unsigned int u = __float_as_uint(f);
    return (unsigned short)((u + 0x7fffu + ((u >> 16) & 1u)) >> 16);
}
__device__ __forceinline__ ushort4 pack4(float a, float b, float c, float d) {
    ushort4 u; u.x = f2bf(a); u.y = f2bf(b); u.z = f2bf(c); u.w = f2bf(d); return u;
}
// async global->LDS, 16B per lane; LDS dest is wave-uniform base + lane*16.
__device__ __forceinline__ void gload16(const unsigned short* g, unsigned short* l) {
    __builtin_amdgcn_global_load_lds(
        (const __attribute__((address_space(1))) unsigned int*)g,
        (__attribute__((address_space(3))) unsigned int*)l, 16, 0, 0);
}

// ---------------------------------------------------------------------------
// Wc[1024][512] bf16 = concat(Wf, Wg, Wh) rows, K-contiguous.
// ---------------------------------------------------------------------------
__global__ __launch_bounds__(256) void convert_w_kernel(
    const float* __restrict__ Wf, const float* __restrict__ Wg,
    const float* __restrict__ Wh, unsigned short* __restrict__ Wc)
{
    const int idx = blockIdx.x * 256 + threadIdx.x;
    const int o  = idx >> 7;
    const int c4 = (idx & 127) * 4;
    const float* src = (o < HCH)     ? (Wf + (size_t)o * CH + c4)
                     : (o < 2 * HCH) ? (Wg + (size_t)(o - HCH) * CH + c4)
                                     : (Wh + (size_t)(o - 2 * HCH) * CH + c4);
    float4 v = *(const float4*)src;
    *(ushort4*)&Wc[(size_t)o * CH + c4] = pack4(v.x, v.y, v.z, v.w);
}

// ---------------------------------------------------------------------------
// X' swizzle: x fp32 [b][512][4096] -> bf16 [b][cb=16][n=4096][co=32].
// ---------------------------------------------------------------------------
__global__ __launch_bounds__(256) void convert_x_kernel(
    const float* __restrict__ x, unsigned short* __restrict__ Xp)
{
    __shared__ unsigned short Lt[64][40];
    const int b  = blockIdx.z;
    const int cb = blockIdx.y;
    const int n0 = blockIdx.x * 64;
    const int t  = threadIdx.x;
    const int cr = t >> 4;
    const int f4 = t & 15;
    #pragma unroll
    for (int p = 0; p < 2; ++p) {
        const int c = p * 16 + cr;
        float4 v = *(const float4*)(x + ((size_t)b * CH + cb * 32 + c) * NPIX + n0 + f4 * 4);
        Lt[f4 * 4 + 0][c] = f2bf(v.x);
        Lt[f4 * 4 + 1][c] = f2bf(v.y);
        Lt[f4 * 4 + 2][c] = f2bf(v.z);
        Lt[f4 * 4 + 3][c] = f2bf(v.w);
    }
    __syncthreads();
    const int n  = t >> 2;
    const int ch = t & 3;
    uint4 u = *(const uint4*)&Lt[n][ch * 8];
    *(uint4*)&Xp[((size_t)b * 16 + cb) * (NPIX * 32) + (size_t)(n0 + n) * 32 + ch * 8] = u;
}

// ---------------------------------------------------------------------------
// proj F/G (verified): G in XOR-swizzled image (el ^= ((n&7)<<3)).
// ---------------------------------------------------------------------------
__global__ __launch_bounds__(256, 4) void proj_fg_kernel(
    const unsigned short* __restrict__ Wc, const unsigned short* __restrict__ Xp,
    const float* __restrict__ bf, const float* __restrict__ bg,
    unsigned short* __restrict__ F, unsigned short* __restrict__ G)
{
    const int b  = blockIdx.z;
    const int n0 = blockIdx.x * 64;
    const int o0 = blockIdx.y * 128;
    const int t  = threadIdx.x;
    const int wave = t >> 6, lane = t & 63, quad = lane >> 4, l16 = lane & 15;
    const int ow = o0 + wave * 32;

    f32x4 acc[2][4];
    #pragma unroll
    for (int ms = 0; ms < 2; ++ms)
        #pragma unroll
        for (int ns = 0; ns < 4; ++ns) acc[ms][ns] = (f32x4){0.f, 0.f, 0.f, 0.f};

    const unsigned short* xb = Xp + (size_t)b * 16 * (NPIX * 32);
    for (int st = 0; st < 16; ++st) {
        bf16x8 a0 = *(const bf16x8*)&Wc[(size_t)(ow + l16) * CH + st * 32 + quad * 8];
        bf16x8 a1 = *(const bf16x8*)&Wc[(size_t)(ow + 16 + l16) * CH + st * 32 + quad * 8];
        const unsigned short* xs = xb + (size_t)st * (NPIX * 32) + quad * 8;
        #pragma unroll
        for (int ns = 0; ns < 4; ++ns) {
            bf16x8 bb = *(const bf16x8*)(xs + (size_t)(n0 + ns * 16 + l16) * 32);
            acc[0][ns] = MFMA16(a0, bb, acc[0][ns]);
            acc[1][ns] = MFMA16(a1, bb, acc[1][ns]);
        }
    }

    const int orow = quad * 4;
    const int gx = (l16 & 7) << 3;   // n&7 == l16&7, ushort units
    #pragma unroll
    for (int ms = 0; ms < 2; ++ms) {
        const int ob = ow + ms * 16 + orow;
        float bias[4];
        #pragma unroll
        for (int r = 0; r < 4; ++r)
            bias[r] = (o0 < HCH) ? bf[ob + r] : bg[ob + r - HCH];
        #pragma unroll
        for (int ns = 0; ns < 4; ++ns) {
            const int n = n0 + ns * 16 + l16;
            ushort4 u = pack4(acc[ms][ns][0] + bias[0], acc[ms][ns][1] + bias[1],
                              acc[ms][ns][2] + bias[2], acc[ms][ns][3] + bias[3]);
            if (o0 < HCH) {
                *(ushort4*)&F[((size_t)b * NPIX + n) * HCH + ob] = u;
            } else {
                const int og = ob - HCH;
                const int cb = og >> 5, co = og & 31;
                const int el = (n * 32 + co) ^ gx;   // swizzled image
                *(ushort4*)&G[((size_t)b * 8 + cb) * (NPIX * 32) + el] = u;
            }
        }
    }
}

// ---------------------------------------------------------------------------
// proj V (verified): [b][kb=128][c=512][ko=32], el ^= ((c&7)<<3).
// ---------------------------------------------------------------------------
__global__ __launch_bounds__(256, 4) void proj_v_kernel(
    const unsigned short* __restrict__ Wc, const unsigned short* __restrict__ Xp,
    const float* __restrict__ bh, unsigned short* __restrict__ V)
{
    const int b  = blockIdx.z;
    const int c0 = blockIdx.x * 64;
    const int p0 = blockIdx.y * 128;
    const int t  = threadIdx.x;
    const int wave = t >> 6, lane = t & 63, quad = lane >> 4, l16 = lane & 15;
    const int pw = p0 + wave * 32;

    f32x4 acc[2][4];
    #pragma unroll
    for (int ms = 0; ms < 2; ++ms)
        #pragma unroll
        for (int ns = 0; ns < 4; ++ns) acc[ms][ns] = (f32x4){0.f, 0.f, 0.f, 0.f};

    const unsigned short* xb = Xp + (size_t)b * 16 * (NPIX * 32);
    for (int st = 0; st < 16; ++st) {
        const unsigned short* xs = xb + (size_t)st * (NPIX * 32) + quad * 8;
        bf16x8 a0 = *(const bf16x8*)(xs + (size_t)(pw + l16) * 32);
        bf16x8 a1 = *(const bf16x8*)(xs + (size_t)(pw + 16 + l16) * 32);
        #pragma unroll
        for (int ns = 0; ns < 4; ++ns) {
            bf16x8 bb = *(const bf16x8*)&Wc[(size_t)(2 * HCH + c0 + ns * 16 + l16) * CH + st * 32 + quad * 8];
            acc[0][ns] = MFMA16(a0, bb, acc[0][ns]);
            acc[1][ns] = MFMA16(a1, bb, acc[1][ns]);
        }
    }

    float biasv[4];
    #pragma unroll
    for (int ns = 0; ns < 4; ++ns) biasv[ns] = bh[c0 + ns * 16 + l16];

    const int kb = pw >> 5;
    const int ko0 = quad * 4;
    const int cx = (l16 & 7) << 3;
    #pragma unroll
    for (int ms = 0; ms < 2; ++ms) {
        #pragma unroll
        for (int ns = 0; ns < 4; ++ns) {
            const int c = c0 + ns * 16 + l16;
            ushort4 u = pack4(acc[ms][ns][0] + biasv[ns], acc[ms][ns][1] + biasv[ns],
                              acc[ms][ns][2] + biasv[ns], acc[ms][ns][3] + biasv[ns]);
            const int el = (c * 32 + ms * 16 + ko0) ^ cx;
            *(ushort4*)&V[((size_t)b * 128 + kb) * (CH * 32) + el] = u;
        }
    }
}

// ---------------------------------------------------------------------------
// score v3 (round-7 verified): LDS-staged QK^T with counted vmcnt.
// ---------------------------------------------------------------------------
__global__ __launch_bounds__(512, 4) void score_kernel(
    const unsigned short* __restrict__ F, const unsigned short* __restrict__ G,
    unsigned short* __restrict__ P, float* __restrict__ rowl)
{
    __shared__ unsigned short Gl[2][8 * 64 * 32];   // 2 x 32 KB
    const int blk = blockIdx.x;
    const int xcd = blk & 7;
    const int b   = xcd >> 1;
    const int kh  = xcd & 1;
    const int q0  = (blk >> 3) * 64;
    const int t    = threadIdx.x;
    const int wave = t >> 6, lane = t & 63, quad = lane >> 4, l16 = lane & 15;
    const int qh = wave >> 2, kw = wave & 3;

    bf16x8 af[2][8];
    #pragma unroll
    for (int qs = 0; qs < 2; ++qs)
        #pragma unroll
        for (int st = 0; st < 8; ++st)
            af[qs][st] = *(const bf16x8*)&F[((size_t)b * NPIX + q0 + qh * 32 + qs * 16 + l16) * HCH + st * 32 + quad * 8];

    float ls[2][4];
    #pragma unroll
    for (int qs = 0; qs < 2; ++qs)
        #pragma unroll
        for (int r = 0; r < 4; ++r) ls[qs][r] = 0.f;

    const unsigned short* Gb = G + (size_t)b * 8 * (NPIX * 32);
    unsigned short* Pb2 = P + (size_t)b * 128 * (NPIX * 32) + (size_t)(q0 + qh * 32) * 32;
    const int qx = (quad & 1) * 4;

    const int kbeg = kh * 2048;

    auto stage = [&](int bb, int kt) {
        const size_t kofs = (size_t)(kbeg + kt * 64) * 32;
        #pragma unroll
        for (int j = 0; j < 4; ++j) {
            const int cbse = j * 512 + wave * 64;
            const int cb   = cbse >> 8;
            const int o16  = cbse & 255;
            const unsigned short* g = Gb + (size_t)cb * (NPIX * 32) + kofs
                                        + o16 * 8 + lane * 8;
            gload16(g, &Gl[bb][cb * 2048 + o16 * 8]);
        }
    };

    const int fx = (l16 & 7) << 4;
    const int bO = (((kw * 16 + l16) * 64) + quad * 16) ^ fx;

    stage(0, 0);

    int buf = 0;
    for (int kt = 0; kt < 32; ++kt) {
        if (kt == 0) asm volatile("s_waitcnt vmcnt(0)" ::: "memory");
        else         asm volatile("s_waitcnt vmcnt(4)" ::: "memory");
        __builtin_amdgcn_s_barrier();
        __builtin_amdgcn_sched_barrier(0);

        if (kt + 1 < 32) stage(buf ^ 1, kt + 1);   // stays in flight all iter

        f32x4 s[2];
        s[0] = (f32x4){0.f, 0.f, 0.f, 0.f};
        s[1] = (f32x4){0.f, 0.f, 0.f, 0.f};
        const char* gb = (const char*)&Gl[buf][0];
        #pragma unroll
        for (int st = 0; st < 8; ++st) {
            bf16x8 bb = *(const bf16x8*)(gb + st * 4096 + bO);
            s[0] = MFMA16(af[0][st], bb, s[0]);
            s[1] = MFMA16(af[1][st], bb, s[1]);
        }

        const int kkk = kbeg + kt * 64 + kw * 16;
        unsigned short* pw = Pb2 + (size_t)(kkk >> 5) * (NPIX * 32);
        const int kcol = (kw & 1) * 16 + l16;
        #pragma unroll
        for (int qs = 0; qs < 2; ++qs)
            #pragma unroll
            for (int r = 0; r < 4; ++r) {
                float e = exp2f(L2E * s[qs][r]);
                const int el = ((qs * 16 + quad * 4 + r) * 32 + kcol) ^ ((qx + r) << 3);
                pw[el] = f2bf(e);
                ls[qs][r] += e;
            }
        buf ^= 1;
    }

    #pragma unroll
    for (int d = 1; d < 16; d <<= 1)
        #pragma unroll
        for (int qs = 0; qs < 2; ++qs)
            #pragma unroll
            for (int r = 0; r < 4; ++r) ls[qs][r] += __shfl_xor(ls[qs][r], d, 64);

    if (l16 == 0) {
        #pragma unroll
        for (int qs = 0; qs < 2; ++qs)
            #pragma unroll
            for (int r = 0; r < 4; ++r)
                atomicAdd(&rowl[(size_t)b * NPIX + q0 + qh * 32 + qs * 16 + quad * 4 + r], ls[qs][r]);
    }
}

// ---------------------------------------------------------------------------
// pv v5: q-tile 128 (was 64). Round-8 diagnosis: per-step time is pinned by
// shared THROUGHPUT (L2->LDS 42 B/cyc/CU = 75% of L2 ceiling; LDS R+W
// 108 B/cyc ~ port ceiling), not latency -- counted-vmcnt slack was neutral.
// V L2 traffic scales 1/Q: Q=64 -> 1.02 GB of V reads; Q=128 halves it.
// 512 thr (8 waves = 2 qh x 4 cw; per-wave tile 64q x 64c IDENTICAL to the
// verified round-8 code). Grid 256 = 1 blk/CU. Stage = 3 uniform gload16
// per wave (2 V + 1 P shared by 8 waves) -> vmcnt(3); triple buffer 72 KB.
// ---------------------------------------------------------------------------
__global__ __launch_bounds__(512, 2) void pv_kernel(
    const unsigned short* __restrict__ P, const unsigned short* __restrict__ V,
    const float* __restrict__ rowl, float* __restrict__ outres)
{
    __shared__ unsigned short Pl[3][128 * 32];    // 3 x  8 KB
    __shared__ unsigned short Vl[3][256 * 32];    // 3 x 16 KB
    const int blk = blockIdx.x;
    const int xcd = blk & 7;
    const int b   = xcd >> 1;
    const int ch  = xcd & 1;
    const int q0  = (blk >> 3) * 128;
    const int t    = threadIdx.x;
    const int wave = t >> 6, lane = t & 63, quad = lane >> 4, l16 = lane & 15;
    const int qh = wave >> 2;            // 0..1 -> 64-q half
    const int cw = wave & 3;             // 0..3 -> 64-c strip
    const int cbase = cw * 64;

    const unsigned short* Pg = P + ((size_t)b * 128 * NPIX + q0) * 32;
    const unsigned short* Vg = V + ((size_t)b * 128 * CH + ch * 256) * 32;

    // swizzled ds_read byte offsets (constant over k loop)
    const int fx  = (l16 & 7) << 4;
    const int pA0 = (((qh * 64 +  0 + l16) * 64) + quad * 16) ^ fx;
    const int pA1 = (((qh * 64 + 16 + l16) * 64) + quad * 16) ^ fx;
    const int pA2 = (((qh * 64 + 32 + l16) * 64) + quad * 16) ^ fx;
    const int pA3 = (((qh * 64 + 48 + l16) * 64) + quad * 16) ^ fx;
    const int vO0 = (((cbase +  0 + l16) * 64) + quad * 16) ^ fx;
    const int vO1 = (((cbase + 16 + l16) * 64) + quad * 16) ^ fx;
    const int vO2 = (((cbase + 32 + l16) * 64) + quad * 16) ^ fx;
    const int vO3 = (((cbase + 48 + l16) * 64) + quad * 16) ^ fx;

    f32x4 O[4][4];
    #pragma unroll
    for (int i = 0; i < 4; ++i)
        #pragma unroll
        for (int j = 0; j < 4; ++j) O[i][j] = (f32x4){0.f, 0.f, 0.f, 0.f};

    // stage tile kb into buffer bb: uniform 3 gload16 per wave (2 V + 1 P).
    auto stage = [&](int bb, int kb) {
        const unsigned short* vg = Vg + (size_t)kb * (CH * 32) + wave * 1024;
        unsigned short* vl = &Vl[bb][wave * 1024];
        gload16(vg + lane * 8,       vl);
        gload16(vg + 512 + lane * 8, vl + 512);
        const unsigned short* pg = Pg + (size_t)kb * (NPIX * 32) + wave * 512;
        gload16(pg + lane * 8, &Pl[bb][wave * 512]);
    };

    auto compute = [&](int bb) {
        const char* pb = (const char*)&Pl[bb][0];
        const char* vb = (const char*)&Vl[bb][0];
        bf16x8 a0 = *(const bf16x8*)(pb + pA0);
        bf16x8 a1 = *(const bf16x8*)(pb + pA1);
        bf16x8 a2 = *(const bf16x8*)(pb + pA2);
        bf16x8 a3 = *(const bf16x8*)(pb + pA3);
        bf16x8 v0 = *(const bf16x8*)(vb + vO0);
        bf16x8 v1 = *(const bf16x8*)(vb + vO1);
        bf16x8 v2 = *(const bf16x8*)(vb + vO2);
        bf16x8 v3 = *(const bf16x8*)(vb + vO3);
        O[0][0] = MFMA16(a0, v0, O[0][0]);
        O[1][0] = MFMA16(a1, v0, O[1][0]);
        O[2][0] = MFMA16(a2, v0, O[2][0]);
        O[3][0] = MFMA16(a3, v0, O[3][0]);
        O[0][1] = MFMA16(a0, v1, O[0][1]);
        O[1][1] = MFMA16(a1, v1, O[1][1]);
        O[2][1] = MFMA16(a2, v1, O[2][1]);
        O[3][1] = MFMA16(a3, v1, O[3][1]);
        O[0][2] = MFMA16(a0, v2, O[0][2]);
        O[1][2] = MFMA16(a1, v2, O[1][2]);
        O[2][2] = MFMA16(a2, v2, O[2][2]);
        O[3][2] = MFMA16(a3, v2, O[3][2]);
        O[0][3] = MFMA16(a0, v3, O[0][3]);
        O[1][3] = MFMA16(a1, v3, O[1][3]);
        O[2][3] = MFMA16(a2, v3, O[2][3]);
        O[3][3] = MFMA16(a3, v3, O[3][3]);
    };

    stage(0, 0);
    stage(1, 1);

    int buf = 0, pre = 2;
    for (int kb = 0; kb < 127; ++kb) {
        // queue: [3 loads tile kb][3 loads tile kb+1] -> vmcnt(3) retires kb.
        asm volatile("s_waitcnt vmcnt(3)" ::: "memory");
        __builtin_amdgcn_s_barrier();
        __builtin_amdgcn_sched_barrier(0);
        if (kb + 2 < 128) stage(pre, kb + 2);   // in flight for 2 k-steps
        compute(buf);
        buf = (buf == 2) ? 0 : buf + 1;
        pre = (pre == 2) ? 0 : pre + 1;
    }
    // peeled last step: only tile 127's 3 loads remain
    asm volatile("s_waitcnt vmcnt(0)" ::: "memory");
    __builtin_amdgcn_s_barrier();
    __builtin_amdgcn_sched_barrier(0);
    compute(buf);

    float lr[4][4];
    #pragma unroll
    for (int i = 0; i < 4; ++i)
        #pragma unroll
        for (int r = 0; r < 4; ++r)
            lr[i][r] = 1.0f / rowl[(size_t)b * NPIX + q0 + qh * 64 + i * 16 + quad * 4 + r];

    const int cb2 = ch * 256 + cbase;
    #pragma unroll
    for (int i = 0; i < 4; ++i) {
        #pragma unroll
        for (int j = 0; j < 4; ++j) {
            f32x4 o = O[i][j];
            o[0] *= lr[i][0]; o[1] *= lr[i][1]; o[2] *= lr[i][2]; o[3] *= lr[i][3];
            const int c = cb2 + j * 16 + l16;
            *(f32x4*)&outres[((size_t)b * CH + c) * NPIX + q0 + qh * 64 + i * 16 + quad * 4] = o;
        }
    }
}

// ---------------------------------------------------------------------------
// colsum (unchanged, verified).
// ---------------------------------------------------------------------------
__global__ __launch_bounds__(256) void colsum_kernel(
    const unsigned short* __restrict__ P, const float* __restrict__ rowl,
    float* __restrict__ attnacc)
{
    __shared__ float CS[16][32];
    const int blk = blockIdx.x;            // b*128 + kb
    const int b  = blk >> 7;
    const int kb = blk & 127;
    const int t  = threadIdx.x;
    const int ko2 = t & 15;
    const int qr  = t >> 4;
    const unsigned short* Pb = P + (size_t)(b * 128 + kb) * (NPIX * 32);
    const float* rl = rowl + (size_t)b * NPIX;
    const int qx = (qr & 7) << 3;

    float a0 = 0.f, a1 = 0.f;
    for (int q = qr; q < NPIX; q += 16) {
        unsigned int u = *(const unsigned int*)(Pb + ((q * 32 + ko2 * 2) ^ qx));
        float li = 1.0f / rl[q];
        a0 += __uint_as_float(u << 16) * li;
        a1 += __uint_as_float(u & 0xFFFF0000u) * li;
    }
    CS[qr][ko2 * 2]     = a0;
    CS[qr][ko2 * 2 + 1] = a1;
    __syncthreads();
    if (t < 32) {
        float s = 0.f;
        #pragma unroll
        for (int i = 0; i < 16; ++i) s += CS[i][t];
        attnacc[(size_t)b * NPIX + kb * 32 + t] = s;
    }
}

// ---------------------------------------------------------------------------
// FALLBACK path (only if ws_size too small): stats+apply with swizzled reads.
// ---------------------------------------------------------------------------
__global__ __launch_bounds__(512, 4) void stats_kernel(
    const unsigned short* __restrict__ F, const unsigned short* __restrict__ G,
    float* __restrict__ rowl)
{
    const int blk = blockIdx.x;
    const int xcd = blk & 7;
    const int b   = xcd >> 1;
    const int kh  = xcd & 1;
    const int q0  = (blk >> 3) * 64;
    const int t    = threadIdx.x;
    const int wave = t >> 6, lane = t & 63, quad = lane >> 4, l16 = lane & 15;
    const int qh = wave >> 2, kw = wave & 3;
    const int gx = (l16 & 7) << 3;

    bf16x8 af[2][8];
    #pragma unroll
    for (int qs = 0; qs < 2; ++qs)
        #pragma unroll
        for (int st = 0; st < 8; ++st)
            af[qs][st] = *(const bf16x8*)&F[((size_t)b * NPIX + q0 + qh * 32 + qs * 16 + l16) * HCH + st * 32 + quad * 8];

    float ls[2][4];
    #pragma unroll
    for (int qs = 0; qs < 2; ++qs)
        #pragma unroll
        for (int r = 0; r < 4; ++r) ls[qs][r] = 0.f;

    const unsigned short* Gb = G + (size_t)b * 8 * (NPIX * 32);
    const int kbeg = kh * 2048, kend = kbeg + 2048;
    for (int k0 = kbeg; k0 < kend; k0 += 128) {
        const int kk = k0 + kw * 32;
        f32x4 s[2][2];
        #pragma unroll
        for (int qs = 0; qs < 2; ++qs)
            #pragma unroll
            for (int ks = 0; ks < 2; ++ks) s[qs][ks] = (f32x4){0.f, 0.f, 0.f, 0.f};
        #pragma unroll
        for (int st = 0; st < 8; ++st) {
            const unsigned short* gs = Gb + (size_t)st * (NPIX * 32);
            bf16x8 b0 = *(const bf16x8*)(gs + ((((kk + l16) * 32) + quad * 8) ^ gx));
            bf16x8 b1 = *(const bf16x8*)(gs + ((((kk + 16 + l16) * 32) + quad * 8) ^ gx));
            s[0][0] = MFMA16(af[0][st], b0, s[0][0]);
            s[1][0] = MFMA16(af[1][st], b0, s[1][0]);
            s[0][1] = MFMA16(af[0][st], b1, s[0][1]);
            s[1][1] = MFMA16(af[1][st], b1, s[1][1]);
        }
        #pragma unroll
        for (int qs = 0; qs < 2; ++qs)
            #pragma unroll
            for (int r = 0; r < 4; ++r)
                ls[qs][r] += exp2f(L2E * s[qs][0][r]) + exp2f(L2E * s[qs][1][r]);
    }

    #pragma unroll
    for (int d = 1; d < 16; d <<= 1)
        #pragma unroll
        for (int qs = 0; qs < 2; ++qs)
            #pragma unroll
            for (int r = 0; r < 4; ++r) ls[qs][r] += __shfl_xor(ls[qs][r], d, 64);

    if (l16 == 0) {
        #pragma unroll
        for (int qs = 0; qs < 2; ++qs)
            #pragma unroll
            for (int r = 0; r < 4; ++r)
                atomicAdd(&rowl[(size_t)b * NPIX + q0 + qh * 32 + qs * 16 + quad * 4 + r], ls[qs][r]);
    }
}

__global__ __launch_bounds__(512, 4) void apply_kernel(
    const unsigned short* __restrict__ F, const unsigned short* __restrict__ G,
    const unsigned short* __restrict__ V, const float* __restrict__ rowl,
    float* __restrict__ outres, float* __restrict__ attnacc)
{
    __shared__ unsigned short Pl[2][32][136];
    const int blk = blockIdx.x;
    const int xcd = blk & 7;
    const int b   = xcd >> 1;
    const int ch  = xcd & 1;
    const int q0  = (blk >> 3) * 32;
    const int t    = threadIdx.x;
    const int wave = t >> 6, lane = t & 63, quad = lane >> 4, l16 = lane & 15;
    const int cw = ch * 256 + wave * 32;
    const int vx = (l16 & 7) << 3;
    const int gx = (l16 & 7) << 3;

    float linv[2][4];
    #pragma unroll
    for (int qs = 0; qs < 2; ++qs)
        #pragma unroll
        for (int r = 0; r < 4; ++r)
            linv[qs][r] = 1.0f / rowl[(size_t)b * NPIX + q0 + qs * 16 + quad * 4 + r];

    f32x4 O[2][2];
    #pragma unroll
    for (int qs = 0; qs < 2; ++qs)
        #pragma unroll
        for (int ct = 0; ct < 2; ++ct) O[qs][ct] = (f32x4){0.f, 0.f, 0.f, 0.f};

    const unsigned short* Gb = G + (size_t)b * 8 * (NPIX * 32);
    const unsigned short* Vb = V + (size_t)b * 128 * (CH * 32);
    const unsigned short* Fq = F + ((size_t)b * NPIX + q0) * HCH;

    int buf = 0;
    for (int k0 = 0; k0 < NPIX; k0 += 128) {
        const int kk = k0 + wave * 16;
        f32x4 s[2];
        s[0] = (f32x4){0.f, 0.f, 0.f, 0.f};
        s[1] = (f32x4){0.f, 0.f, 0.f, 0.f};
        #pragma unroll
        for (int st = 0; st < 8; ++st) {
            bf16x8 a0 = *(const bf16x8*)&Fq[(size_t)l16 * HCH + st * 32 + quad * 8];
            bf16x8 a1 = *(const bf16x8*)&Fq[(size_t)(16 + l16) * HCH + st * 32 + quad * 8];
            bf16x8 bg = *(const bf16x8*)(Gb + (size_t)st * (NPIX * 32)
                                         + ((((kk + l16) * 32) + quad * 8) ^ gx));
            s[0] = MFMA16(a0, bg, s[0]);
            s[1] = MFMA16(a1, bg, s[1]);
        }

        float p[2][4];
        #pragma unroll
        for (int qs = 0; qs < 2; ++qs)
            #pragma unroll
            for (int r = 0; r < 4; ++r)
                p[qs][r] = exp2f(L2E * s[qs][r]) * linv[qs][r];

        #pragma unroll
        for (int qs = 0; qs < 2; ++qs)
            #pragma unroll
            for (int r = 0; r < 4; ++r)
                Pl[buf][qs * 16 + quad * 4 + r][wave * 16 + l16] = f2bf(p[qs][r]);

        if (ch == 0) {
            float cs = p[0][0] + p[0][1] + p[0][2] + p[0][3]
                     + p[1][0] + p[1][1] + p[1][2] + p[1][3];
            cs += __shfl_xor(cs, 16, 64);
            cs += __shfl_xor(cs, 32, 64);
            if (quad == 0)
                atomicAdd(&attnacc[(size_t)b * NPIX + kk + l16], cs);
        }

        __syncthreads();

        #pragma unroll
        for (int ks = 0; ks < 4; ++ks) {
            bf16x8 pa0 = *(const bf16x8*)&Pl[buf][l16][ks * 32 + quad * 8];
            bf16x8 pa1 = *(const bf16x8*)&Pl[buf][16 + l16][ks * 32 + quad * 8];
            const unsigned short* vs = Vb + ((size_t)(k0 >> 5) + ks) * (CH * 32);
            #pragma unroll
            for (int ct = 0; ct < 2; ++ct) {
                const int el = (((cw + ct * 16 + l16) * 32) + quad * 8) ^ vx;
                bf16x8 vv = *(const bf16x8*)(vs + el);
                O[0][ct] = MFMA16(pa0, vv, O[0][ct]);
                O[1][ct] = MFMA16(pa1, vv, O[1][ct]);
            }
        }
        buf ^= 1;
    }

    #pragma unroll
    for (int qs = 0; qs < 2; ++qs) {
        #pragma unroll
        for (int ct = 0; ct < 2; ++ct) {
            const int c = cw + ct * 16 + l16;
            *(f32x4*)&outres[((size_t)b * CH + c) * NPIX + q0 + qs * 16 + quad * 4] = O[qs][ct];
        }
    }
}

__global__ __launch_bounds__(256) void attn_fin_kernel(
    const float* __restrict__ acc, float* __restrict__ outa)
{
    const int i = blockIdx.x * 256 + threadIdx.x;
    if (i < BATCH * NPIX) outa[i] = acc[i] * (1.0f / (float)NPIX);
}

extern "C" void kernel_launch(void* const* d_in, const int* in_sizes, int n_in,
                              void* d_out, int out_size, void* d_ws, size_t ws_size,
                              hipStream_t stream)
{
    (void)in_sizes; (void)n_in; (void)out_size;
    const float* x  = (const float*)d_in[0];
    const float* Wf = (const float*)d_in[1];
    const float* bf = (const float*)d_in[2];
    const float* Wg = (const float*)d_in[3];
    const float* bg = (const float*)d_in[4];
    const float* Wh = (const float*)d_in[5];
    const float* bh = (const float*)d_in[6];
    float* out = (float*)d_out;

    const size_t P_ELEMS  = (size_t)BATCH * 128 * NPIX * 32;   // 67,108,864
    const size_t XP_ELEMS = (size_t)BATCH * 16 * NPIX * 32;    //  8,388,608
    const size_t F_ELEMS  = (size_t)BATCH * NPIX * HCH;        //  4,194,304
    const size_t V_ELEMS  = (size_t)BATCH * 128 * CH * 32;     //  8,388,608
    const size_t NEED = (P_ELEMS + 2 * F_ELEMS + V_ELEMS) * 2
                      + (size_t)2 * BATCH * NPIX * 4;          // ~167.9 MB

    if (ws_size >= NEED) {
        // ---- materialized-P path. P overlays Xp+Wc (dead before score).
        unsigned short* P  = (unsigned short*)d_ws;
        unsigned short* Xp = P;
        unsigned short* Wc = P + XP_ELEMS;
        unsigned short* F  = P + P_ELEMS;
        unsigned short* G  = F + F_ELEMS;
        unsigned short* V  = G + F_ELEMS;
        float* rowl    = (float*)(V + V_ELEMS);
        float* attnacc = rowl + (size_t)BATCH * NPIX;

        hipMemsetAsync(rowl, 0, (size_t)BATCH * NPIX * sizeof(float), stream);

        convert_w_kernel<<<512, 256, 0, stream>>>(Wf, Wg, Wh, Wc);
        convert_x_kernel<<<dim3(NPIX / 64, 16, BATCH), 256, 0, stream>>>(x, Xp);

        proj_fg_kernel<<<dim3(NPIX / 64, 4, BATCH), 256, 0, stream>>>(Wc, Xp, bf, bg, F, G);
        proj_v_kernel<<<dim3(8, NPIX / 128, BATCH), 256, 0, stream>>>(Wc, Xp, bh, V);

        score_kernel<<<512, 512, 0, stream>>>(F, G, P, rowl);
        pv_kernel<<<256, 512, 0, stream>>>(P, V, rowl, out);
        colsum_kernel<<<512, 256, 0, stream>>>(P, rowl, attnacc);

        attn_fin_kernel<<<BATCH * NPIX / 256, 256, 0, stream>>>(
            attnacc, out + (size_t)BATCH * CH * NPIX);
    } else {
        // ---- fallback: stats+apply (G/V images swizzled; readers XOR).
        unsigned short* Xp = (unsigned short*)d_ws;
        unsigned short* Wc = Xp + XP_ELEMS;
        unsigned short* F  = Wc + (size_t)1024 * CH;
        unsigned short* G  = F + F_ELEMS;
        unsigned short* V  = G + F_ELEMS;
        float* rowl    = (float*)(V + V_ELEMS);
        float* attnacc = rowl + (size_t)BATCH * NPIX;

        hipMemsetAsync(rowl, 0, (size_t)2 * BATCH * NPIX * sizeof(float), stream);

        convert_w_kernel<<<512, 256, 0, stream>>>(Wf, Wg, Wh, Wc);
        convert_x_kernel<<<dim3(NPIX / 64, 16, BATCH), 256, 0, stream>>>(x, Xp);

        proj_fg_kernel<<<dim3(NPIX / 64, 4, BATCH), 256, 0, stream>>>(Wc, Xp, bf, bg, F, G);
        proj_v_kernel<<<dim3(8, NPIX / 128, BATCH), 256, 0, stream>>>(Wc, Xp, bh, V);

        stats_kernel<<<512, 512, 0, stream>>>(F, G, rowl);
        apply_kernel<<<1024, 512, 0, stream>>>(F, G, V, rowl, out, attnacc);

        attn_fin_kernel<<<BATCH * NPIX / 256, 256, 0, stream>>>(
            attnacc, out + (size_t)BATCH * CH * NPIX);
    }
}

// Round 10
// 404.834 us; speedup vs baseline: 1.0490x; 1.0490x over previous
//
#include <hip/hip_runtime.h>
#include <cmath>

#define BATCH 4
#define CH    512
#define HCH   256
#define NPIX  4096
#define L2E   1.44269504088896340736f

typedef __attribute__((ext_vector_type(8))) short bf16x8;
typedef __attribute__((ext_vector_type(4))) float f32x4;

#define MFMA16(a, b, c) __builtin_amdgcn_mfma_f32_16x16x32_bf16((a), (b), (c), 0, 0, 0)

__device__ __forceinline__ unsigned short f2bf(float f) {
    unsigned int u = __float_as_uint(f);
    return (unsigned short)((u + 0x7fffu + ((u >> 16) & 1u)) >> 16);
}
__device__ __forceinline__ ushort4 pack4(float a, float b, float c, float d) {
    ushort4 u; u.x = f2bf(a); u.y = f2bf(b); u.z = f2bf(c); u.w = f2bf(d); return u;
}
// async global->LDS, 16B per lane; LDS dest is wave-uniform base + lane*16.
__device__ __forceinline__ void gload16(const unsigned short* g, unsigned short* l) {
    __builtin_amdgcn_global_load_lds(
        (const __attribute__((address_space(1))) unsigned int*)g,
        (__attribute__((address_space(3))) unsigned int*)l, 16, 0, 0);
}

// ---------------------------------------------------------------------------
// Wc[1024][512] bf16 = concat(Wf, Wg, Wh) rows, K-contiguous.
// ---------------------------------------------------------------------------
__global__ __launch_bounds__(256) void convert_w_kernel(
    const float* __restrict__ Wf, const float* __restrict__ Wg,
    const float* __restrict__ Wh, unsigned short* __restrict__ Wc)
{
    const int idx = blockIdx.x * 256 + threadIdx.x;
    const int o  = idx >> 7;
    const int c4 = (idx & 127) * 4;
    const float* src = (o < HCH)     ? (Wf + (size_t)o * CH + c4)
                     : (o < 2 * HCH) ? (Wg + (size_t)(o - HCH) * CH + c4)
                                     : (Wh + (size_t)(o - 2 * HCH) * CH + c4);
    float4 v = *(const float4*)src;
    *(ushort4*)&Wc[(size_t)o * CH + c4] = pack4(v.x, v.y, v.z, v.w);
}

// ---------------------------------------------------------------------------
// X' swizzle: x fp32 [b][512][4096] -> bf16 [b][cb=16][n=4096][co=32].
// ---------------------------------------------------------------------------
__global__ __launch_bounds__(256) void convert_x_kernel(
    const float* __restrict__ x, unsigned short* __restrict__ Xp)
{
    __shared__ unsigned short Lt[64][40];
    const int b  = blockIdx.z;
    const int cb = blockIdx.y;
    const int n0 = blockIdx.x * 64;
    const int t  = threadIdx.x;
    const int cr = t >> 4;
    const int f4 = t & 15;
    #pragma unroll
    for (int p = 0; p < 2; ++p) {
        const int c = p * 16 + cr;
        float4 v = *(const float4*)(x + ((size_t)b * CH + cb * 32 + c) * NPIX + n0 + f4 * 4);
        Lt[f4 * 4 + 0][c] = f2bf(v.x);
        Lt[f4 * 4 + 1][c] = f2bf(v.y);
        Lt[f4 * 4 + 2][c] = f2bf(v.z);
        Lt[f4 * 4 + 3][c] = f2bf(v.w);
    }
    __syncthreads();
    const int n  = t >> 2;
    const int ch = t & 3;
    uint4 u = *(const uint4*)&Lt[n][ch * 8];
    *(uint4*)&Xp[((size_t)b * 16 + cb) * (NPIX * 32) + (size_t)(n0 + n) * 32 + ch * 8] = u;
}

// ---------------------------------------------------------------------------
// proj F/G (verified): G in XOR-swizzled image (el ^= ((n&7)<<3)).
// ---------------------------------------------------------------------------
__global__ __launch_bounds__(256, 4) void proj_fg_kernel(
    const unsigned short* __restrict__ Wc, const unsigned short* __restrict__ Xp,
    const float* __restrict__ bf, const float* __restrict__ bg,
    unsigned short* __restrict__ F, unsigned short* __restrict__ G)
{
    const int b  = blockIdx.z;
    const int n0 = blockIdx.x * 64;
    const int o0 = blockIdx.y * 128;
    const int t  = threadIdx.x;
    const int wave = t >> 6, lane = t & 63, quad = lane >> 4, l16 = lane & 15;
    const int ow = o0 + wave * 32;

    f32x4 acc[2][4];
    #pragma unroll
    for (int ms = 0; ms < 2; ++ms)
        #pragma unroll
        for (int ns = 0; ns < 4; ++ns) acc[ms][ns] = (f32x4){0.f, 0.f, 0.f, 0.f};

    const unsigned short* xb = Xp + (size_t)b * 16 * (NPIX * 32);
    for (int st = 0; st < 16; ++st) {
        bf16x8 a0 = *(const bf16x8*)&Wc[(size_t)(ow + l16) * CH + st * 32 + quad * 8];
        bf16x8 a1 = *(const bf16x8*)&Wc[(size_t)(ow + 16 + l16) * CH + st * 32 + quad * 8];
        const unsigned short* xs = xb + (size_t)st * (NPIX * 32) + quad * 8;
        #pragma unroll
        for (int ns = 0; ns < 4; ++ns) {
            bf16x8 bb = *(const bf16x8*)(xs + (size_t)(n0 + ns * 16 + l16) * 32);
            acc[0][ns] = MFMA16(a0, bb, acc[0][ns]);
            acc[1][ns] = MFMA16(a1, bb, acc[1][ns]);
        }
    }

    const int orow = quad * 4;
    const int gx = (l16 & 7) << 3;   // n&7 == l16&7, ushort units
    #pragma unroll
    for (int ms = 0; ms < 2; ++ms) {
        const int ob = ow + ms * 16 + orow;
        float bias[4];
        #pragma unroll
        for (int r = 0; r < 4; ++r)
            bias[r] = (o0 < HCH) ? bf[ob + r] : bg[ob + r - HCH];
        #pragma unroll
        for (int ns = 0; ns < 4; ++ns) {
            const int n = n0 + ns * 16 + l16;
            ushort4 u = pack4(acc[ms][ns][0] + bias[0], acc[ms][ns][1] + bias[1],
                              acc[ms][ns][2] + bias[2], acc[ms][ns][3] + bias[3]);
            if (o0 < HCH) {
                *(ushort4*)&F[((size_t)b * NPIX + n) * HCH + ob] = u;
            } else {
                const int og = ob - HCH;
                const int cb = og >> 5, co = og & 31;
                const int el = (n * 32 + co) ^ gx;   // swizzled image
                *(ushort4*)&G[((size_t)b * 8 + cb) * (NPIX * 32) + el] = u;
            }
        }
    }
}

// ---------------------------------------------------------------------------
// proj V (verified): [b][kb=128][c=512][ko=32], el ^= ((c&7)<<3).
// ---------------------------------------------------------------------------
__global__ __launch_bounds__(256, 4) void proj_v_kernel(
    const unsigned short* __restrict__ Wc, const unsigned short* __restrict__ Xp,
    const float* __restrict__ bh, unsigned short* __restrict__ V)
{
    const int b  = blockIdx.z;
    const int c0 = blockIdx.x * 64;
    const int p0 = blockIdx.y * 128;
    const int t  = threadIdx.x;
    const int wave = t >> 6, lane = t & 63, quad = lane >> 4, l16 = lane & 15;
    const int pw = p0 + wave * 32;

    f32x4 acc[2][4];
    #pragma unroll
    for (int ms = 0; ms < 2; ++ms)
        #pragma unroll
        for (int ns = 0; ns < 4; ++ns) acc[ms][ns] = (f32x4){0.f, 0.f, 0.f, 0.f};

    const unsigned short* xb = Xp + (size_t)b * 16 * (NPIX * 32);
    for (int st = 0; st < 16; ++st) {
        const unsigned short* xs = xb + (size_t)st * (NPIX * 32) + quad * 8;
        bf16x8 a0 = *(const bf16x8*)(xs + (size_t)(pw + l16) * 32);
        bf16x8 a1 = *(const bf16x8*)(xs + (size_t)(pw + 16 + l16) * 32);
        #pragma unroll
        for (int ns = 0; ns < 4; ++ns) {
            bf16x8 bb = *(const bf16x8*)&Wc[(size_t)(2 * HCH + c0 + ns * 16 + l16) * CH + st * 32 + quad * 8];
            acc[0][ns] = MFMA16(a0, bb, acc[0][ns]);
            acc[1][ns] = MFMA16(a1, bb, acc[1][ns]);
        }
    }

    float biasv[4];
    #pragma unroll
    for (int ns = 0; ns < 4; ++ns) biasv[ns] = bh[c0 + ns * 16 + l16];

    const int kb = pw >> 5;
    const int ko0 = quad * 4;
    const int cx = (l16 & 7) << 3;
    #pragma unroll
    for (int ms = 0; ms < 2; ++ms) {
        #pragma unroll
        for (int ns = 0; ns < 4; ++ns) {
            const int c = c0 + ns * 16 + l16;
            ushort4 u = pack4(acc[ms][ns][0] + biasv[ns], acc[ms][ns][1] + biasv[ns],
                              acc[ms][ns][2] + biasv[ns], acc[ms][ns][3] + biasv[ns]);
            const int el = (c * 32 + ms * 16 + ko0) ^ cx;
            *(ushort4*)&V[((size_t)b * 128 + kb) * (CH * 32) + el] = u;
        }
    }
}

// ---------------------------------------------------------------------------
// score v3 (round-7 verified): LDS-staged QK^T with counted vmcnt.
// ---------------------------------------------------------------------------
__global__ __launch_bounds__(512, 4) void score_kernel(
    const unsigned short* __restrict__ F, const unsigned short* __restrict__ G,
    unsigned short* __restrict__ P, float* __restrict__ rowl)
{
    __shared__ unsigned short Gl[2][8 * 64 * 32];   // 2 x 32 KB
    const int blk = blockIdx.x;
    const int xcd = blk & 7;
    const int b   = xcd >> 1;
    const int kh  = xcd & 1;
    const int q0  = (blk >> 3) * 64;
    const int t    = threadIdx.x;
    const int wave = t >> 6, lane = t & 63, quad = lane >> 4, l16 = lane & 15;
    const int qh = wave >> 2, kw = wave & 3;

    bf16x8 af[2][8];
    #pragma unroll
    for (int qs = 0; qs < 2; ++qs)
        #pragma unroll
        for (int st = 0; st < 8; ++st)
            af[qs][st] = *(const bf16x8*)&F[((size_t)b * NPIX + q0 + qh * 32 + qs * 16 + l16) * HCH + st * 32 + quad * 8];

    float ls[2][4];
    #pragma unroll
    for (int qs = 0; qs < 2; ++qs)
        #pragma unroll
        for (int r = 0; r < 4; ++r) ls[qs][r] = 0.f;

    const unsigned short* Gb = G + (size_t)b * 8 * (NPIX * 32);
    unsigned short* Pb2 = P + (size_t)b * 128 * (NPIX * 32) + (size_t)(q0 + qh * 32) * 32;
    const int qx = (quad & 1) * 4;

    const int kbeg = kh * 2048;

    auto stage = [&](int bb, int kt) {
        const size_t kofs = (size_t)(kbeg + kt * 64) * 32;
        #pragma unroll
        for (int j = 0; j < 4; ++j) {
            const int cbse = j * 512 + wave * 64;
            const int cb   = cbse >> 8;
            const int o16  = cbse & 255;
            const unsigned short* g = Gb + (size_t)cb * (NPIX * 32) + kofs
                                        + o16 * 8 + lane * 8;
            gload16(g, &Gl[bb][cb * 2048 + o16 * 8]);
        }
    };

    const int fx = (l16 & 7) << 4;
    const int bO = (((kw * 16 + l16) * 64) + quad * 16) ^ fx;

    stage(0, 0);

    int buf = 0;
    for (int kt = 0; kt < 32; ++kt) {
        if (kt == 0) asm volatile("s_waitcnt vmcnt(0)" ::: "memory");
        else         asm volatile("s_waitcnt vmcnt(4)" ::: "memory");
        __builtin_amdgcn_s_barrier();
        __builtin_amdgcn_sched_barrier(0);

        if (kt + 1 < 32) stage(buf ^ 1, kt + 1);   // stays in flight all iter

        f32x4 s[2];
        s[0] = (f32x4){0.f, 0.f, 0.f, 0.f};
        s[1] = (f32x4){0.f, 0.f, 0.f, 0.f};
        const char* gb = (const char*)&Gl[buf][0];
        #pragma unroll
        for (int st = 0; st < 8; ++st) {
            bf16x8 bb = *(const bf16x8*)(gb + st * 4096 + bO);
            s[0] = MFMA16(af[0][st], bb, s[0]);
            s[1] = MFMA16(af[1][st], bb, s[1]);
        }

        const int kkk = kbeg + kt * 64 + kw * 16;
        unsigned short* pw = Pb2 + (size_t)(kkk >> 5) * (NPIX * 32);
        const int kcol = (kw & 1) * 16 + l16;
        #pragma unroll
        for (int qs = 0; qs < 2; ++qs)
            #pragma unroll
            for (int r = 0; r < 4; ++r) {
                float e = exp2f(L2E * s[qs][r]);
                const int el = ((qs * 16 + quad * 4 + r) * 32 + kcol) ^ ((qx + r) << 3);
                pw[el] = f2bf(e);
                ls[qs][r] += e;
            }
        buf ^= 1;
    }

    #pragma unroll
    for (int d = 1; d < 16; d <<= 1)
        #pragma unroll
        for (int qs = 0; qs < 2; ++qs)
            #pragma unroll
            for (int r = 0; r < 4; ++r) ls[qs][r] += __shfl_xor(ls[qs][r], d, 64);

    if (l16 == 0) {
        #pragma unroll
        for (int qs = 0; qs < 2; ++qs)
            #pragma unroll
            for (int r = 0; r < 4; ++r)
                atomicAdd(&rowl[(size_t)b * NPIX + q0 + qh * 32 + qs * 16 + quad * 4 + r], ls[qs][r]);
    }
}

// ---------------------------------------------------------------------------
// pv v6: P direct-to-REGISTER, V-only LDS staging. Round-9 diagnosis: pv is
// LDS-READ-PORT bound (b128 ~12cyc incl. intrinsic overhead; R6 = 76% port
// util with 2 blk/CU; Q=128's 1 blk/CU dropped util to 44% -> slower).
// Cut read volume instead of latency: each wave's P rows are fixed and
// shared by the 4 cw-waves -> load P global->reg (2 coalesced b128/step,
// L1-broadcast, 1-step prefetch) and stage only V (16 KB/step, dbuf 32 KB).
// ds_reads/wave-step 6 -> 4, P ds_writes gone: port floor 78 -> ~54 us.
// Structure otherwise = R6's best-measured pv (512 thr, 8 waves = 2qw x 4cw,
// Q=64, 2 blk/CU, __syncthreads dbuf -- R8 proved drain-vs-counted neutral).
// ---------------------------------------------------------------------------
__global__ __launch_bounds__(512, 4) void pv_kernel(
    const unsigned short* __restrict__ P, const unsigned short* __restrict__ V,
    const float* __restrict__ rowl, float* __restrict__ outres)
{
    __shared__ unsigned short Vl[2][256 * 32];    // 2 x 16 KB
    const int blk = blockIdx.x;
    const int xcd = blk & 7;
    const int b   = xcd >> 1;
    const int ch  = xcd & 1;
    const int q0  = (blk >> 3) * 64;
    const int t    = threadIdx.x;
    const int wave = t >> 6, lane = t & 63, quad = lane >> 4, l16 = lane & 15;
    const int qw = wave >> 2;            // 0..1 -> 32-q strip
    const int cw = wave & 3;             // 0..3 -> 64-c strip
    const int cbase = cw * 64;

    const unsigned short* Pg = P + ((size_t)b * 128 * NPIX + q0) * 32;
    const unsigned short* Vg = V + ((size_t)b * 128 * CH + ch * 256) * 32;

    // P direct-load element offsets in the swizzled global image (constant):
    // el = (row*32 + ko) ^ ((row&7)<<3), row&7 == l16&7. Fully coalesced
    // (wave covers a contiguous 1KB region; XOR permutes within it).
    const int pE0 = (((qw * 32      + l16) * 32) + quad * 8) ^ ((l16 & 7) << 3);
    const int pE1 = (((qw * 32 + 16 + l16) * 32) + quad * 8) ^ ((l16 & 7) << 3);

    // swizzled V ds_read byte offsets (constant over k loop)
    const int fx  = (l16 & 7) << 4;
    const int vO0 = (((cbase +  0 + l16) * 64) + quad * 16) ^ fx;
    const int vO1 = (((cbase + 16 + l16) * 64) + quad * 16) ^ fx;
    const int vO2 = (((cbase + 32 + l16) * 64) + quad * 16) ^ fx;
    const int vO3 = (((cbase + 48 + l16) * 64) + quad * 16) ^ fx;

    f32x4 O[2][4];
    #pragma unroll
    for (int qs = 0; qs < 2; ++qs)
        #pragma unroll
        for (int ct = 0; ct < 4; ++ct) O[qs][ct] = (f32x4){0.f, 0.f, 0.f, 0.f};

    // stage V tile kb into buffer bb: uniform 2 gload16 per wave.
    auto stage = [&](int bb, int kb) {
        const unsigned short* vg = Vg + (size_t)kb * (CH * 32) + wave * 1024;
        unsigned short* vl = &Vl[bb][wave * 1024];
        gload16(vg + lane * 8,       vl);
        gload16(vg + 512 + lane * 8, vl + 512);
    };

    bf16x8 pc0, pc1, pn0, pn1;
    {
        const unsigned short* pg = Pg;
        pc0 = *(const bf16x8*)(pg + pE0);
        pc1 = *(const bf16x8*)(pg + pE1);
    }
    stage(0, 0);
    __syncthreads();

    int buf = 0;
    for (int kb = 0; kb < 128; ++kb) {
        if (kb + 1 < 128) {
            stage(buf ^ 1, kb + 1);
            const unsigned short* pg = Pg + (size_t)(kb + 1) * (NPIX * 32);
            pn0 = *(const bf16x8*)(pg + pE0);
            pn1 = *(const bf16x8*)(pg + pE1);
        }

        const char* vb = (const char*)&Vl[buf][0];
        bf16x8 v0 = *(const bf16x8*)(vb + vO0);
        bf16x8 v1 = *(const bf16x8*)(vb + vO1);
        bf16x8 v2 = *(const bf16x8*)(vb + vO2);
        bf16x8 v3 = *(const bf16x8*)(vb + vO3);
        O[0][0] = MFMA16(pc0, v0, O[0][0]);
        O[1][0] = MFMA16(pc1, v0, O[1][0]);
        O[0][1] = MFMA16(pc0, v1, O[0][1]);
        O[1][1] = MFMA16(pc1, v1, O[1][1]);
        O[0][2] = MFMA16(pc0, v2, O[0][2]);
        O[1][2] = MFMA16(pc1, v2, O[1][2]);
        O[0][3] = MFMA16(pc0, v3, O[0][3]);
        O[1][3] = MFMA16(pc1, v3, O[1][3]);

        __syncthreads();   // V[buf] consumed; next stage writes are safe
        pc0 = pn0; pc1 = pn1;
        buf ^= 1;
    }

    float lr[2][4];
    #pragma unroll
    for (int qs = 0; qs < 2; ++qs)
        #pragma unroll
        for (int r = 0; r < 4; ++r)
            lr[qs][r] = 1.0f / rowl[(size_t)b * NPIX + q0 + qw * 32 + qs * 16 + quad * 4 + r];

    const int cb2 = ch * 256 + cbase;
    #pragma unroll
    for (int qs = 0; qs < 2; ++qs) {
        #pragma unroll
        for (int ct = 0; ct < 4; ++ct) {
            f32x4 o = O[qs][ct];
            o[0] *= lr[qs][0]; o[1] *= lr[qs][1]; o[2] *= lr[qs][2]; o[3] *= lr[qs][3];
            const int c = cb2 + ct * 16 + l16;
            *(f32x4*)&outres[((size_t)b * CH + c) * NPIX + q0 + qw * 32 + qs * 16 + quad * 4] = o;
        }
    }
}

// ---------------------------------------------------------------------------
// colsum (unchanged, verified).
// ---------------------------------------------------------------------------
__global__ __launch_bounds__(256) void colsum_kernel(
    const unsigned short* __restrict__ P, const float* __restrict__ rowl,
    float* __restrict__ attnacc)
{
    __shared__ float CS[16][32];
    const int blk = blockIdx.x;            // b*128 + kb
    const int b  = blk >> 7;
    const int kb = blk & 127;
    const int t  = threadIdx.x;
    const int ko2 = t & 15;
    const int qr  = t >> 4;
    const unsigned short* Pb = P + (size_t)(b * 128 + kb) * (NPIX * 32);
    const float* rl = rowl + (size_t)b * NPIX;
    const int qx = (qr & 7) << 3;

    float a0 = 0.f, a1 = 0.f;
    for (int q = qr; q < NPIX; q += 16) {
        unsigned int u = *(const unsigned int*)(Pb + ((q * 32 + ko2 * 2) ^ qx));
        float li = 1.0f / rl[q];
        a0 += __uint_as_float(u << 16) * li;
        a1 += __uint_as_float(u & 0xFFFF0000u) * li;
    }
    CS[qr][ko2 * 2]     = a0;
    CS[qr][ko2 * 2 + 1] = a1;
    __syncthreads();
    if (t < 32) {
        float s = 0.f;
        #pragma unroll
        for (int i = 0; i < 16; ++i) s += CS[i][t];
        attnacc[(size_t)b * NPIX + kb * 32 + t] = s;
    }
}

// ---------------------------------------------------------------------------
// FALLBACK path (only if ws_size too small): stats+apply with swizzled reads.
// ---------------------------------------------------------------------------
__global__ __launch_bounds__(512, 4) void stats_kernel(
    const unsigned short* __restrict__ F, const unsigned short* __restrict__ G,
    float* __restrict__ rowl)
{
    const int blk = blockIdx.x;
    const int xcd = blk & 7;
    const int b   = xcd >> 1;
    const int kh  = xcd & 1;
    const int q0  = (blk >> 3) * 64;
    const int t    = threadIdx.x;
    const int wave = t >> 6, lane = t & 63, quad = lane >> 4, l16 = lane & 15;
    const int qh = wave >> 2, kw = wave & 3;
    const int gx = (l16 & 7) << 3;

    bf16x8 af[2][8];
    #pragma unroll
    for (int qs = 0; qs < 2; ++qs)
        #pragma unroll
        for (int st = 0; st < 8; ++st)
            af[qs][st] = *(const bf16x8*)&F[((size_t)b * NPIX + q0 + qh * 32 + qs * 16 + l16) * HCH + st * 32 + quad * 8];

    float ls[2][4];
    #pragma unroll
    for (int qs = 0; qs < 2; ++qs)
        #pragma unroll
        for (int r = 0; r < 4; ++r) ls[qs][r] = 0.f;

    const unsigned short* Gb = G + (size_t)b * 8 * (NPIX * 32);
    const int kbeg = kh * 2048, kend = kbeg + 2048;
    for (int k0 = kbeg; k0 < kend; k0 += 128) {
        const int kk = k0 + kw * 32;
        f32x4 s[2][2];
        #pragma unroll
        for (int qs = 0; qs < 2; ++qs)
            #pragma unroll
            for (int ks = 0; ks < 2; ++ks) s[qs][ks] = (f32x4){0.f, 0.f, 0.f, 0.f};
        #pragma unroll
        for (int st = 0; st < 8; ++st) {
            const unsigned short* gs = Gb + (size_t)st * (NPIX * 32);
            bf16x8 b0 = *(const bf16x8*)(gs + ((((kk + l16) * 32) + quad * 8) ^ gx));
            bf16x8 b1 = *(const bf16x8*)(gs + ((((kk + 16 + l16) * 32) + quad * 8) ^ gx));
            s[0][0] = MFMA16(af[0][st], b0, s[0][0]);
            s[1][0] = MFMA16(af[1][st], b0, s[1][0]);
            s[0][1] = MFMA16(af[0][st], b1, s[0][1]);
            s[1][1] = MFMA16(af[1][st], b1, s[1][1]);
        }
        #pragma unroll
        for (int qs = 0; qs < 2; ++qs)
            #pragma unroll
            for (int r = 0; r < 4; ++r)
                ls[qs][r] += exp2f(L2E * s[qs][0][r]) + exp2f(L2E * s[qs][1][r]);
    }

    #pragma unroll
    for (int d = 1; d < 16; d <<= 1)
        #pragma unroll
        for (int qs = 0; qs < 2; ++qs)
            #pragma unroll
            for (int r = 0; r < 4; ++r) ls[qs][r] += __shfl_xor(ls[qs][r], d, 64);

    if (l16 == 0) {
        #pragma unroll
        for (int qs = 0; qs < 2; ++qs)
            #pragma unroll
            for (int r = 0; r < 4; ++r)
                atomicAdd(&rowl[(size_t)b * NPIX + q0 + qh * 32 + qs * 16 + quad * 4 + r], ls[qs][r]);
    }
}

__global__ __launch_bounds__(512, 4) void apply_kernel(
    const unsigned short* __restrict__ F, const unsigned short* __restrict__ G,
    const unsigned short* __restrict__ V, const float* __restrict__ rowl,
    float* __restrict__ outres, float* __restrict__ attnacc)
{
    __shared__ unsigned short Pl[2][32][136];
    const int blk = blockIdx.x;
    const int xcd = blk & 7;
    const int b   = xcd >> 1;
    const int ch  = xcd & 1;
    const int q0  = (blk >> 3) * 32;
    const int t    = threadIdx.x;
    const int wave = t >> 6, lane = t & 63, quad = lane >> 4, l16 = lane & 15;
    const int cw = ch * 256 + wave * 32;
    const int vx = (l16 & 7) << 3;
    const int gx = (l16 & 7) << 3;

    float linv[2][4];
    #pragma unroll
    for (int qs = 0; qs < 2; ++qs)
        #pragma unroll
        for (int r = 0; r < 4; ++r)
            linv[qs][r] = 1.0f / rowl[(size_t)b * NPIX + q0 + qs * 16 + quad * 4 + r];

    f32x4 O[2][2];
    #pragma unroll
    for (int qs = 0; qs < 2; ++qs)
        #pragma unroll
        for (int ct = 0; ct < 2; ++ct) O[qs][ct] = (f32x4){0.f, 0.f, 0.f, 0.f};

    const unsigned short* Gb = G + (size_t)b * 8 * (NPIX * 32);
    const unsigned short* Vb = V + (size_t)b * 128 * (CH * 32);
    const unsigned short* Fq = F + ((size_t)b * NPIX + q0) * HCH;

    int buf = 0;
    for (int k0 = 0; k0 < NPIX; k0 += 128) {
        const int kk = k0 + wave * 16;
        f32x4 s[2];
        s[0] = (f32x4){0.f, 0.f, 0.f, 0.f};
        s[1] = (f32x4){0.f, 0.f, 0.f, 0.f};
        #pragma unroll
        for (int st = 0; st < 8; ++st) {
            bf16x8 a0 = *(const bf16x8*)&Fq[(size_t)l16 * HCH + st * 32 + quad * 8];
            bf16x8 a1 = *(const bf16x8*)&Fq[(size_t)(16 + l16) * HCH + st * 32 + quad * 8];
            bf16x8 bg = *(const bf16x8*)(Gb + (size_t)st * (NPIX * 32)
                                         + ((((kk + l16) * 32) + quad * 8) ^ gx));
            s[0] = MFMA16(a0, bg, s[0]);
            s[1] = MFMA16(a1, bg, s[1]);
        }

        float p[2][4];
        #pragma unroll
        for (int qs = 0; qs < 2; ++qs)
            #pragma unroll
            for (int r = 0; r < 4; ++r)
                p[qs][r] = exp2f(L2E * s[qs][r]) * linv[qs][r];

        #pragma unroll
        for (int qs = 0; qs < 2; ++qs)
            #pragma unroll
            for (int r = 0; r < 4; ++r)
                Pl[buf][qs * 16 + quad * 4 + r][wave * 16 + l16] = f2bf(p[qs][r]);

        if (ch == 0) {
            float cs = p[0][0] + p[0][1] + p[0][2] + p[0][3]
                     + p[1][0] + p[1][1] + p[1][2] + p[1][3];
            cs += __shfl_xor(cs, 16, 64);
            cs += __shfl_xor(cs, 32, 64);
            if (quad == 0)
                atomicAdd(&attnacc[(size_t)b * NPIX + kk + l16], cs);
        }

        __syncthreads();

        #pragma unroll
        for (int ks = 0; ks < 4; ++ks) {
            bf16x8 pa0 = *(const bf16x8*)&Pl[buf][l16][ks * 32 + quad * 8];
            bf16x8 pa1 = *(const bf16x8*)&Pl[buf][16 + l16][ks * 32 + quad * 8];
            const unsigned short* vs = Vb + ((size_t)(k0 >> 5) + ks) * (CH * 32);
            #pragma unroll
            for (int ct = 0; ct < 2; ++ct) {
                const int el = (((cw + ct * 16 + l16) * 32) + quad * 8) ^ vx;
                bf16x8 vv = *(const bf16x8*)(vs + el);
                O[0][ct] = MFMA16(pa0, vv, O[0][ct]);
                O[1][ct] = MFMA16(pa1, vv, O[1][ct]);
            }
        }
        buf ^= 1;
    }

    #pragma unroll
    for (int qs = 0; qs < 2; ++qs) {
        #pragma unroll
        for (int ct = 0; ct < 2; ++ct) {
            const int c = cw + ct * 16 + l16;
            *(f32x4*)&outres[((size_t)b * CH + c) * NPIX + q0 + qs * 16 + quad * 4] = O[qs][ct];
        }
    }
}

__global__ __launch_bounds__(256) void attn_fin_kernel(
    const float* __restrict__ acc, float* __restrict__ outa)
{
    const int i = blockIdx.x * 256 + threadIdx.x;
    if (i < BATCH * NPIX) outa[i] = acc[i] * (1.0f / (float)NPIX);
}

extern "C" void kernel_launch(void* const* d_in, const int* in_sizes, int n_in,
                              void* d_out, int out_size, void* d_ws, size_t ws_size,
                              hipStream_t stream)
{
    (void)in_sizes; (void)n_in; (void)out_size;
    const float* x  = (const float*)d_in[0];
    const float* Wf = (const float*)d_in[1];
    const float* bf = (const float*)d_in[2];
    const float* Wg = (const float*)d_in[3];
    const float* bg = (const float*)d_in[4];
    const float* Wh = (const float*)d_in[5];
    const float* bh = (const float*)d_in[6];
    float* out = (float*)d_out;

    const size_t P_ELEMS  = (size_t)BATCH * 128 * NPIX * 32;   // 67,108,864
    const size_t XP_ELEMS = (size_t)BATCH * 16 * NPIX * 32;    //  8,388,608
    const size_t F_ELEMS  = (size_t)BATCH * NPIX * HCH;        //  4,194,304
    const size_t V_ELEMS  = (size_t)BATCH * 128 * CH * 32;     //  8,388,608
    const size_t NEED = (P_ELEMS + 2 * F_ELEMS + V_ELEMS) * 2
                      + (size_t)2 * BATCH * NPIX * 4;          // ~167.9 MB

    if (ws_size >= NEED) {
        // ---- materialized-P path. P overlays Xp+Wc (dead before score).
        unsigned short* P  = (unsigned short*)d_ws;
        unsigned short* Xp = P;
        unsigned short* Wc = P + XP_ELEMS;
        unsigned short* F  = P + P_ELEMS;
        unsigned short* G  = F + F_ELEMS;
        unsigned short* V  = G + F_ELEMS;
        float* rowl    = (float*)(V + V_ELEMS);
        float* attnacc = rowl + (size_t)BATCH * NPIX;

        hipMemsetAsync(rowl, 0, (size_t)BATCH * NPIX * sizeof(float), stream);

        convert_w_kernel<<<512, 256, 0, stream>>>(Wf, Wg, Wh, Wc);
        convert_x_kernel<<<dim3(NPIX / 64, 16, BATCH), 256, 0, stream>>>(x, Xp);

        proj_fg_kernel<<<dim3(NPIX / 64, 4, BATCH), 256, 0, stream>>>(Wc, Xp, bf, bg, F, G);
        proj_v_kernel<<<dim3(8, NPIX / 128, BATCH), 256, 0, stream>>>(Wc, Xp, bh, V);

        score_kernel<<<512, 512, 0, stream>>>(F, G, P, rowl);
        pv_kernel<<<512, 512, 0, stream>>>(P, V, rowl, out);
        colsum_kernel<<<512, 256, 0, stream>>>(P, rowl, attnacc);

        attn_fin_kernel<<<BATCH * NPIX / 256, 256, 0, stream>>>(
            attnacc, out + (size_t)BATCH * CH * NPIX);
    } else {
        // ---- fallback: stats+apply (G/V images swizzled; readers XOR).
        unsigned short* Xp = (unsigned short*)d_ws;
        unsigned short* Wc = Xp + XP_ELEMS;
        unsigned short* F  = Wc + (size_t)1024 * CH;
        unsigned short* G  = F + F_ELEMS;
        unsigned short* V  = G + F_ELEMS;
        float* rowl    = (float*)(V + V_ELEMS);
        float* attnacc = rowl + (size_t)BATCH * NPIX;

        hipMemsetAsync(rowl, 0, (size_t)2 * BATCH * NPIX * sizeof(float), stream);

        convert_w_kernel<<<512, 256, 0, stream>>>(Wf, Wg, Wh, Wc);
        convert_x_kernel<<<dim3(NPIX / 64, 16, BATCH), 256, 0, stream>>>(x, Xp);

        proj_fg_kernel<<<dim3(NPIX / 64, 4, BATCH), 256, 0, stream>>>(Wc, Xp, bf, bg, F, G);
        proj_v_kernel<<<dim3(8, NPIX / 128, BATCH), 256, 0, stream>>>(Wc, Xp, bh, V);

        stats_kernel<<<512, 512, 0, stream>>>(F, G, rowl);
        apply_kernel<<<1024, 512, 0, stream>>>(F, G, V, rowl, out, attnacc);

        attn_fin_kernel<<<BATCH * NPIX / 256, 256, 0, stream>>>(
            attnacc, out + (size_t)BATCH * CH * NPIX);
    }
}